// Round 5
// baseline (436.121 us; speedup 1.0000x reference)
//
#include <hip/hip_runtime.h>
#include <hip/hip_bf16.h>

// GCNBlock: fused 7-dispatch pipeline.
// h' = (x@W)*dinv stored bf16 ; gather-aggregate ; graph-LayerNorm ; PReLU
// N=50000, E=800000, F=256

#define F 256
#define EPSV 1e-5f

typedef __attribute__((ext_vector_type(8))) short short8;
typedef __attribute__((ext_vector_type(4))) float f32x4;

__device__ __forceinline__ unsigned short f2bf(float f) {
  union { float f; unsigned u; } v; v.f = f;
  unsigned r = v.u + 0x7fffu + ((v.u >> 16) & 1u);  // RNE
  return (unsigned short)(r >> 16);
}

__device__ __forceinline__ float bf2f(unsigned short u) {
  union { unsigned u; float f; } v; v.u = ((unsigned)u) << 16; return v.f;
}

// ---- 1 kernel: degree count ------------------------------------------------

__global__ void count_deg(const int* __restrict__ dst, int* __restrict__ deg_cnt, int E) {
  int e = blockIdx.x * blockDim.x + threadIdx.x;
  if (e < E) atomicAdd(&deg_cnt[dst[e]], 1);
}

// ---- 1 kernel: [block 0] full CSR scan + dinv ; [blocks 1..64] prep_W ------
// prep_W layout: Wb[((t*8+kc)*64+lane)*8+j] = bf16(W[kc*32+(lane>>4)*8+j][t*16+(lane&15)])

__global__ void scan_prep(const int* __restrict__ deg_cnt, int* __restrict__ csr_ptr,
                          float* __restrict__ dinv, int N, int E,
                          const float* __restrict__ W, unsigned short* __restrict__ Wb) {
  if (blockIdx.x == 0) {
    const int C = (N + 1023) / 1024;  // per-thread chunk
    int t = threadIdx.x;
    int base = t * C;
    int s = 0;
    for (int j = 0; j < C; ++j) {
      int i = base + j;
      if (i < N) s += deg_cnt[i];
    }
    __shared__ int ls[1024];
    ls[t] = s;
    __syncthreads();
    for (int off = 1; off < 1024; off <<= 1) {
      int v = (t >= off) ? ls[t - off] : 0;
      __syncthreads();
      ls[t] += v;
      __syncthreads();
    }
    int run = ls[t] - s;  // exclusive prefix
    for (int j = 0; j < C; ++j) {
      int i = base + j;
      if (i < N) {
        int d = deg_cnt[i];
        csr_ptr[i] = run;
        run += d;
        dinv[i] = rsqrtf((float)(d + 1));
      }
    }
    if (t == 1023) csr_ptr[N] = E;
  } else {
    int gid = (blockIdx.x - 1) * 1024 + threadIdx.x;  // 65536 total
    int j = gid & 7;
    int lane = (gid >> 3) & 63;
    int kc = (gid >> 9) & 7;
    int tt = gid >> 12;
    int k = kc * 32 + (lane >> 4) * 8 + j;
    int n = tt * 16 + (lane & 15);
    Wb[gid] = f2bf(W[k * 256 + n]);
  }
}

// ---- 1 kernel: [blocks 0..eb) fill_csr ; [blocks eb..) gemm ----------------
// gemm: block handles 16 rows x 256 cols; wave w -> cols w*64..; h' = (x@W)*dinv, bf16

__global__ void fill_gemm(const int* __restrict__ src, const int* __restrict__ dst,
                          const int* __restrict__ csr_ptr, int* __restrict__ csr_fill,
                          int* __restrict__ csr_src, int E, int eb,
                          const float* __restrict__ x, const unsigned short* __restrict__ Wb,
                          const float* __restrict__ dinv, ushort4* __restrict__ hb, int N) {
  __shared__ unsigned short lds[16][264];  // gemm repack; +8 pad breaks bank alias

  if ((int)blockIdx.x < eb) {
    int e = blockIdx.x * 256 + threadIdx.x;
    if (e < E) {
      int d = dst[e];
      int pos = csr_ptr[d] + atomicAdd(&csr_fill[d], 1);
      csr_src[pos] = src[e];
    }
    return;
  }

  int bid = blockIdx.x - eb;
  int lane = threadIdx.x & 63;
  int wave = threadIdx.x >> 6;
  int m0 = bid * 16;
  int q = lane >> 4;

  int row = m0 + (lane & 15);
  int rowc = row < N ? row : N - 1;

  f32x4 acc[4] = {{0,0,0,0},{0,0,0,0},{0,0,0,0},{0,0,0,0}};

  for (int kc = 0; kc < 8; ++kc) {
    int koff = kc * 32 + q * 8;
    const float4* xp = (const float4*)(x + (size_t)rowc * F + koff);
    float4 a0 = xp[0];
    float4 a1 = xp[1];
    short8 a;
    a[0] = f2bf(a0.x); a[1] = f2bf(a0.y); a[2] = f2bf(a0.z); a[3] = f2bf(a0.w);
    a[4] = f2bf(a1.x); a[5] = f2bf(a1.y); a[6] = f2bf(a1.z); a[7] = f2bf(a1.w);
#pragma unroll
    for (int tt = 0; tt < 4; ++tt) {
      const short8 b = *(const short8*)(Wb + (((wave * 4 + tt) * 8 + kc) * 64 + lane) * 8);
      acc[tt] = __builtin_amdgcn_mfma_f32_16x16x32_bf16(a, b, acc[tt], 0, 0, 0);
    }
  }

  int crow = q * 4;
  int ccol = lane & 15;
#pragma unroll
  for (int rr = 0; rr < 4; ++rr) {
    int orow = m0 + crow + rr;
    float dv = (orow < N) ? dinv[orow] : 0.f;
#pragma unroll
    for (int tt = 0; tt < 4; ++tt) {
      lds[crow + rr][wave * 64 + tt * 16 + ccol] = f2bf(acc[tt][rr] * dv);
    }
  }
  __syncthreads();
  int t = threadIdx.x;
  int lrow = t >> 4;
  int grow = m0 + lrow;
  if (grow < N) {
#pragma unroll
    for (int it = 0; it < 4; ++it) {
      int c4 = (t & 15) + 16 * it;  // ushort4 index 0..63
      ushort4 u = *(const ushort4*)&lds[lrow][c4 * 4];
      hb[(size_t)grow * 64 + c4] = u;
    }
  }
}

// ---- Aggregation: one row per wave, 16-way unrolled bf16 gather ------------
// Per-block (sum, sumsq) -> partials[blk], no global atomics.

__global__ void aggregate(const ushort4* __restrict__ hb, const int* __restrict__ csr_ptr,
                          const int* __restrict__ csr_src, const float* __restrict__ dinv,
                          const float* __restrict__ conv_bias, float4* __restrict__ out,
                          double2* __restrict__ partials, int N) {
  int wave = threadIdx.x >> 6;
  int lane = threadIdx.x & 63;
  int row = blockIdx.x * 4 + wave;
  float s1 = 0.f, s2 = 0.f;

  if (row < N) {
    float di = dinv[row];
    int b0 = csr_ptr[row], b1 = csr_ptr[row + 1];
    ushort4 self = hb[(size_t)row * 64 + lane];
    float4 acc;
    acc.x = bf2f(self.x); acc.y = bf2f(self.y);
    acc.z = bf2f(self.z); acc.w = bf2f(self.w);

    for (int e = b0; e < b1; e += 16) {
      int idx[16];
#pragma unroll
      for (int j = 0; j < 16; ++j) {
        int ee = e + j;
        idx[j] = csr_src[ee < b1 ? ee : b1 - 1];
      }
      ushort4 v[16];
#pragma unroll
      for (int j = 0; j < 16; ++j) v[j] = hb[(size_t)idx[j] * 64 + lane];
#pragma unroll
      for (int j = 0; j < 16; ++j) {
        float m = (e + j < b1) ? 1.f : 0.f;
        acc.x = fmaf(bf2f(v[j].x), m, acc.x);
        acc.y = fmaf(bf2f(v[j].y), m, acc.y);
        acc.z = fmaf(bf2f(v[j].z), m, acc.z);
        acc.w = fmaf(bf2f(v[j].w), m, acc.w);
      }
    }

    float4 b = *(const float4*)(conv_bias + lane * 4);
    acc.x = fmaf(acc.x, di, b.x);
    acc.y = fmaf(acc.y, di, b.y);
    acc.z = fmaf(acc.z, di, b.z);
    acc.w = fmaf(acc.w, di, b.w);
    out[(size_t)row * 64 + lane] = acc;
    s1 = acc.x + acc.y + acc.z + acc.w;
    s2 = acc.x * acc.x + acc.y * acc.y + acc.z * acc.z + acc.w * acc.w;
  }

  __shared__ float r1[256];
  __shared__ float r2[256];
  int t = threadIdx.x;
  r1[t] = s1;
  r2[t] = s2;
  __syncthreads();
  for (int off = 128; off > 0; off >>= 1) {
    if (t < off) { r1[t] += r1[t + off]; r2[t] += r2[t + off]; }
    __syncthreads();
  }
  if (t == 0) {
    double2 pp;
    pp.x = (double)r1[0];
    pp.y = (double)r2[0];
    partials[blockIdx.x] = pp;
  }
}

__global__ void finalize_stats(const double2* __restrict__ partials, int nb,
                               float* __restrict__ stats, double cnt) {
  __shared__ double q1[1024];
  __shared__ double q2[1024];
  int t = threadIdx.x;
  double a1 = 0.0, a2 = 0.0;
  for (int i = t; i < nb; i += 1024) {
    double2 pp = partials[i];
    a1 += pp.x;
    a2 += pp.y;
  }
  q1[t] = a1;
  q2[t] = a2;
  __syncthreads();
  for (int off = 512; off > 0; off >>= 1) {
    if (t < off) { q1[t] += q1[t + off]; q2[t] += q2[t + off]; }
    __syncthreads();
  }
  if (t == 0) {
    double mu = q1[0] / cnt;
    double var = q2[0] / cnt - mu * mu;
    if (var < 0) var = 0;
    double sd = sqrt(var);
    stats[0] = (float)mu;
    stats[1] = (float)(1.0 / (sd + (double)EPSV));
  }
}

__global__ void norm_prelu(float4* __restrict__ out, const float* __restrict__ stats,
                           const float* __restrict__ lw, const float* __restrict__ lb,
                           const float* __restrict__ pa, int n4) {
  int i = blockIdx.x * blockDim.x + threadIdx.x;
  if (i >= n4) return;
  float mu = stats[0];
  float inv = stats[1];
  float a = pa[0];
  int c4 = (i & 63) * 4;
  float4 w = *(const float4*)(lw + c4);
  float4 b = *(const float4*)(lb + c4);
  float4 v = out[i];
  float y0 = (v.x - mu) * inv * w.x + b.x;
  float y1 = (v.y - mu) * inv * w.y + b.y;
  float y2 = (v.z - mu) * inv * w.z + b.z;
  float y3 = (v.w - mu) * inv * w.w + b.w;
  v.x = y0 >= 0.f ? y0 : a * y0;
  v.y = y1 >= 0.f ? y1 : a * y1;
  v.z = y2 >= 0.f ? y2 : a * y2;
  v.w = y3 >= 0.f ? y3 : a * y3;
  out[i] = v;
}

// ---- launch ---------------------------------------------------------------

extern "C" void kernel_launch(void* const* d_in, const int* in_sizes, int n_in,
                              void* d_out, int out_size, void* d_ws, size_t ws_size,
                              hipStream_t stream) {
  const float* x = (const float*)d_in[0];
  const int* eidx = (const int*)d_in[1];
  const float* W = (const float*)d_in[3];
  const float* conv_bias = (const float*)d_in[4];
  const float* ln_w = (const float*)d_in[5];
  const float* ln_b = (const float*)d_in[6];
  const float* prelu_a = (const float*)d_in[7];
  float* out = (float*)d_out;

  int N = in_sizes[0] / F;
  int E = in_sizes[1] / 2;
  const int* src = eidx;
  const int* dst = eidx + E;

  int nAggBlocks = (N + 3) / 4;
  int eb = (E + 255) / 256;
  int gemmb = (N + 15) / 16;

  char* p = (char*)d_ws;
  auto carve = [&](size_t bytes) { char* r = p; p += (bytes + 255) & ~(size_t)255; return r; };
  ushort4* hb    = (ushort4*)carve((size_t)N * 64 * sizeof(ushort4));  // bf16 h'
  unsigned short* Wb = (unsigned short*)carve((size_t)F * F * sizeof(short));
  int* zero2     = (int*)carve((size_t)2 * N * sizeof(int));  // deg_cnt | csr_fill
  int* deg_cnt   = zero2;
  int* csr_fill  = zero2 + N;
  float* dinv    = (float*)carve((size_t)N * sizeof(float));
  int* csr_ptr   = (int*)carve((size_t)(N + 1) * sizeof(int));
  int* csr_src   = (int*)carve((size_t)E * sizeof(int));
  double2* partials = (double2*)carve((size_t)nAggBlocks * sizeof(double2));
  float* stats   = (float*)carve(2 * sizeof(float));

  hipMemsetAsync(zero2, 0, (size_t)2 * N * sizeof(int), stream);

  count_deg<<<eb, 256, 0, stream>>>(dst, deg_cnt, E);
  scan_prep<<<1 + (F * F + 1023) / 1024, 1024, 0, stream>>>(deg_cnt, csr_ptr, dinv, N, E, W, Wb);
  fill_gemm<<<eb + gemmb, 256, 0, stream>>>(src, dst, csr_ptr, csr_fill, csr_src, E, eb,
                                            x, Wb, dinv, hb, N);
  aggregate<<<nAggBlocks, 256, 0, stream>>>(hb, csr_ptr, csr_src, dinv,
                                            conv_bias, (float4*)out, partials, N);
  finalize_stats<<<1, 1024, 0, stream>>>(partials, nAggBlocks, stats,
                                         (double)N * (double)F);
  int n4 = N * (F / 4);
  norm_prelu<<<(n4 + 255) / 256, 256, 0, stream>>>((float4*)out, stats, ln_w, ln_b, prelu_a, n4);
}

// Round 6
// 291.340 us; speedup vs baseline: 1.4969x; 1.4969x over previous
//
#include <hip/hip_runtime.h>
#include <hip/hip_bf16.h>

// GCNBlock: 9-dispatch pipeline, parallel scan, single atomic pass.
// h' = (x@W)*dinv stored bf16 ; gather-aggregate ; graph-LayerNorm ; PReLU
// N=50000, E=800000, F=256

#define F 256
#define EPSV 1e-5f

typedef __attribute__((ext_vector_type(8))) short short8;
typedef __attribute__((ext_vector_type(4))) float f32x4;

__device__ __forceinline__ unsigned short f2bf(float f) {
  union { float f; unsigned u; } v; v.f = f;
  unsigned r = v.u + 0x7fffu + ((v.u >> 16) & 1u);  // RNE
  return (unsigned short)(r >> 16);
}

__device__ __forceinline__ float bf2f(unsigned short u) {
  union { unsigned u; float f; } v; v.u = ((unsigned)u) << 16; return v.f;
}

// ---- count + rank (edges) ; prep_W (blocks >= eb) --------------------------
// rank[e] = this edge's arrival index among edges with same dst -> fill needs no atomics.

__global__ void count_rank(const int* __restrict__ dst, int* __restrict__ deg_cnt,
                           int* __restrict__ rank, int E, int eb,
                           const float* __restrict__ W, unsigned short* __restrict__ Wb) {
  if ((int)blockIdx.x < eb) {
    int e = blockIdx.x * 256 + threadIdx.x;
    if (e < E) rank[e] = atomicAdd(&deg_cnt[dst[e]], 1);
    return;
  }
  int gid = (blockIdx.x - eb) * 256 + threadIdx.x;  // 65536 total
  int j = gid & 7;
  int lane = (gid >> 3) & 63;
  int kc = (gid >> 9) & 7;
  int tt = gid >> 12;
  int k = kc * 32 + (lane >> 4) * 8 + j;
  int n = tt * 16 + (lane & 15);
  Wb[gid] = f2bf(W[k * 256 + n]);
}

// ---- parallel scan chain (3 small kernels) ---------------------------------

__global__ void block_sums(const int* __restrict__ deg_cnt, int* __restrict__ bsum,
                           float* __restrict__ dinv, int N) {
  __shared__ int s[256];
  int t = threadIdx.x;
  int i = blockIdx.x * 256 + t;
  int d = (i < N) ? deg_cnt[i] : 0;
  if (i < N) dinv[i] = rsqrtf((float)(d + 1));  // +1 self loop
  s[t] = d;
  __syncthreads();
  for (int off = 128; off > 0; off >>= 1) {
    if (t < off) s[t] += s[t + off];
    __syncthreads();
  }
  if (t == 0) bsum[blockIdx.x] = s[0];
}

__global__ void scan_bsums(const int* __restrict__ bsum, int* __restrict__ boff, int nb) {
  __shared__ int s[256];
  int t = threadIdx.x;
  int v = (t < nb) ? bsum[t] : 0;
  s[t] = v;
  __syncthreads();
  for (int off = 1; off < 256; off <<= 1) {
    int x = (t >= off) ? s[t - off] : 0;
    __syncthreads();
    s[t] += x;
    __syncthreads();
  }
  if (t < nb) boff[t] = s[t] - v;  // exclusive
}

__global__ void write_csr(const int* __restrict__ deg_cnt, const int* __restrict__ boff,
                          int* __restrict__ csr_ptr, int N, int E) {
  __shared__ int s[256];
  int t = threadIdx.x;
  int i = blockIdx.x * 256 + t;
  int v = (i < N) ? deg_cnt[i] : 0;
  s[t] = v;
  __syncthreads();
  for (int off = 1; off < 256; off <<= 1) {
    int x = (t >= off) ? s[t - off] : 0;
    __syncthreads();
    s[t] += x;
    __syncthreads();
  }
  if (i < N) csr_ptr[i] = boff[blockIdx.x] + s[t] - v;
  if (i == 0) csr_ptr[N] = E;
}

// ---- fill (atomic-free, blocks < eb) ; gemm (blocks >= eb) -----------------

__global__ void fill_gemm(const int* __restrict__ src, const int* __restrict__ dst,
                          const int* __restrict__ rank, const int* __restrict__ csr_ptr,
                          int* __restrict__ csr_src, int E, int eb,
                          const float* __restrict__ x, const unsigned short* __restrict__ Wb,
                          const float* __restrict__ dinv, ushort4* __restrict__ hb, int N) {
  __shared__ unsigned short lds[16][264];  // gemm repack; +8 pad breaks bank alias

  if ((int)blockIdx.x < eb) {
    int e = blockIdx.x * 256 + threadIdx.x;
    if (e < E) {
      int d = dst[e];
      csr_src[csr_ptr[d] + rank[e]] = src[e];
    }
    return;
  }

  int bid = blockIdx.x - eb;
  int lane = threadIdx.x & 63;
  int wave = threadIdx.x >> 6;
  int m0 = bid * 16;
  int q = lane >> 4;

  int row = m0 + (lane & 15);
  int rowc = row < N ? row : N - 1;

  f32x4 acc[4] = {{0,0,0,0},{0,0,0,0},{0,0,0,0},{0,0,0,0}};

  for (int kc = 0; kc < 8; ++kc) {
    int koff = kc * 32 + q * 8;
    const float4* xp = (const float4*)(x + (size_t)rowc * F + koff);
    float4 a0 = xp[0];
    float4 a1 = xp[1];
    short8 a;
    a[0] = f2bf(a0.x); a[1] = f2bf(a0.y); a[2] = f2bf(a0.z); a[3] = f2bf(a0.w);
    a[4] = f2bf(a1.x); a[5] = f2bf(a1.y); a[6] = f2bf(a1.z); a[7] = f2bf(a1.w);
#pragma unroll
    for (int tt = 0; tt < 4; ++tt) {
      const short8 b = *(const short8*)(Wb + (((wave * 4 + tt) * 8 + kc) * 64 + lane) * 8);
      acc[tt] = __builtin_amdgcn_mfma_f32_16x16x32_bf16(a, b, acc[tt], 0, 0, 0);
    }
  }

  int crow = q * 4;
  int ccol = lane & 15;
#pragma unroll
  for (int rr = 0; rr < 4; ++rr) {
    int orow = m0 + crow + rr;
    float dv = (orow < N) ? dinv[orow] : 0.f;
#pragma unroll
    for (int tt = 0; tt < 4; ++tt) {
      lds[crow + rr][wave * 64 + tt * 16 + ccol] = f2bf(acc[tt][rr] * dv);
    }
  }
  __syncthreads();
  int t = threadIdx.x;
  int lrow = t >> 4;
  int grow = m0 + lrow;
  if (grow < N) {
#pragma unroll
    for (int it = 0; it < 4; ++it) {
      int c4 = (t & 15) + 16 * it;  // ushort4 index 0..63
      ushort4 u = *(const ushort4*)&lds[lrow][c4 * 4];
      hb[(size_t)grow * 64 + c4] = u;
    }
  }
}

// ---- Aggregation: one row per wave, 16-way unrolled bf16 gather ------------

__global__ void aggregate(const ushort4* __restrict__ hb, const int* __restrict__ csr_ptr,
                          const int* __restrict__ csr_src, const float* __restrict__ dinv,
                          const float* __restrict__ conv_bias, float4* __restrict__ out,
                          double2* __restrict__ partials, int N) {
  int wave = threadIdx.x >> 6;
  int lane = threadIdx.x & 63;
  int row = blockIdx.x * 4 + wave;
  float s1 = 0.f, s2 = 0.f;

  if (row < N) {
    float di = dinv[row];
    int b0 = csr_ptr[row], b1 = csr_ptr[row + 1];
    ushort4 self = hb[(size_t)row * 64 + lane];
    float4 acc;
    acc.x = bf2f(self.x); acc.y = bf2f(self.y);
    acc.z = bf2f(self.z); acc.w = bf2f(self.w);

    for (int e = b0; e < b1; e += 16) {
      int idx[16];
#pragma unroll
      for (int j = 0; j < 16; ++j) {
        int ee = e + j;
        idx[j] = csr_src[ee < b1 ? ee : b1 - 1];
      }
      ushort4 v[16];
#pragma unroll
      for (int j = 0; j < 16; ++j) v[j] = hb[(size_t)idx[j] * 64 + lane];
#pragma unroll
      for (int j = 0; j < 16; ++j) {
        float m = (e + j < b1) ? 1.f : 0.f;
        acc.x = fmaf(bf2f(v[j].x), m, acc.x);
        acc.y = fmaf(bf2f(v[j].y), m, acc.y);
        acc.z = fmaf(bf2f(v[j].z), m, acc.z);
        acc.w = fmaf(bf2f(v[j].w), m, acc.w);
      }
    }

    float4 b = *(const float4*)(conv_bias + lane * 4);
    acc.x = fmaf(acc.x, di, b.x);
    acc.y = fmaf(acc.y, di, b.y);
    acc.z = fmaf(acc.z, di, b.z);
    acc.w = fmaf(acc.w, di, b.w);
    out[(size_t)row * 64 + lane] = acc;
    s1 = acc.x + acc.y + acc.z + acc.w;
    s2 = acc.x * acc.x + acc.y * acc.y + acc.z * acc.z + acc.w * acc.w;
  }

  __shared__ float r1[256];
  __shared__ float r2[256];
  int t = threadIdx.x;
  r1[t] = s1;
  r2[t] = s2;
  __syncthreads();
  for (int off = 128; off > 0; off >>= 1) {
    if (t < off) { r1[t] += r1[t + off]; r2[t] += r2[t + off]; }
    __syncthreads();
  }
  if (t == 0) {
    double2 pp;
    pp.x = (double)r1[0];
    pp.y = (double)r2[0];
    partials[blockIdx.x] = pp;
  }
}

__global__ void finalize_stats(const double2* __restrict__ partials, int nb,
                               float* __restrict__ stats, double cnt) {
  __shared__ double q1[1024];
  __shared__ double q2[1024];
  int t = threadIdx.x;
  double a1 = 0.0, a2 = 0.0;
  for (int i = t; i < nb; i += 1024) {
    double2 pp = partials[i];
    a1 += pp.x;
    a2 += pp.y;
  }
  q1[t] = a1;
  q2[t] = a2;
  __syncthreads();
  for (int off = 512; off > 0; off >>= 1) {
    if (t < off) { q1[t] += q1[t + off]; q2[t] += q2[t + off]; }
    __syncthreads();
  }
  if (t == 0) {
    double mu = q1[0] / cnt;
    double var = q2[0] / cnt - mu * mu;
    if (var < 0) var = 0;
    double sd = sqrt(var);
    stats[0] = (float)mu;
    stats[1] = (float)(1.0 / (sd + (double)EPSV));
  }
}

__global__ void norm_prelu(float4* __restrict__ out, const float* __restrict__ stats,
                           const float* __restrict__ lw, const float* __restrict__ lb,
                           const float* __restrict__ pa, int n4) {
  int i = blockIdx.x * blockDim.x + threadIdx.x;
  if (i >= n4) return;
  float mu = stats[0];
  float inv = stats[1];
  float a = pa[0];
  int c4 = (i & 63) * 4;
  float4 w = *(const float4*)(lw + c4);
  float4 b = *(const float4*)(lb + c4);
  float4 v = out[i];
  float y0 = (v.x - mu) * inv * w.x + b.x;
  float y1 = (v.y - mu) * inv * w.y + b.y;
  float y2 = (v.z - mu) * inv * w.z + b.z;
  float y3 = (v.w - mu) * inv * w.w + b.w;
  v.x = y0 >= 0.f ? y0 : a * y0;
  v.y = y1 >= 0.f ? y1 : a * y1;
  v.z = y2 >= 0.f ? y2 : a * y2;
  v.w = y3 >= 0.f ? y3 : a * y3;
  out[i] = v;
}

// ---- launch ---------------------------------------------------------------

extern "C" void kernel_launch(void* const* d_in, const int* in_sizes, int n_in,
                              void* d_out, int out_size, void* d_ws, size_t ws_size,
                              hipStream_t stream) {
  const float* x = (const float*)d_in[0];
  const int* eidx = (const int*)d_in[1];
  const float* W = (const float*)d_in[3];
  const float* conv_bias = (const float*)d_in[4];
  const float* ln_w = (const float*)d_in[5];
  const float* ln_b = (const float*)d_in[6];
  const float* prelu_a = (const float*)d_in[7];
  float* out = (float*)d_out;

  int N = in_sizes[0] / F;
  int E = in_sizes[1] / 2;
  const int* src = eidx;
  const int* dst = eidx + E;

  int nAggBlocks = (N + 3) / 4;
  int eb = (E + 255) / 256;
  int gemmb = (N + 15) / 16;
  int NB = (N + 255) / 256;

  char* p = (char*)d_ws;
  auto carve = [&](size_t bytes) { char* r = p; p += (bytes + 255) & ~(size_t)255; return r; };
  ushort4* hb    = (ushort4*)carve((size_t)N * 64 * sizeof(ushort4));  // bf16 h'
  unsigned short* Wb = (unsigned short*)carve((size_t)F * F * sizeof(short));
  int* deg_cnt   = (int*)carve((size_t)N * sizeof(int));
  int* rank      = (int*)carve((size_t)E * sizeof(int));
  float* dinv    = (float*)carve((size_t)N * sizeof(float));
  int* csr_ptr   = (int*)carve((size_t)(N + 1) * sizeof(int));
  int* csr_src   = (int*)carve((size_t)E * sizeof(int));
  int* bsum      = (int*)carve((size_t)NB * sizeof(int));
  int* boff      = (int*)carve((size_t)NB * sizeof(int));
  double2* partials = (double2*)carve((size_t)nAggBlocks * sizeof(double2));
  float* stats   = (float*)carve(2 * sizeof(float));

  hipMemsetAsync(deg_cnt, 0, (size_t)N * sizeof(int), stream);

  count_rank<<<eb + 256, 256, 0, stream>>>(dst, deg_cnt, rank, E, eb, W, Wb);
  block_sums<<<NB, 256, 0, stream>>>(deg_cnt, bsum, dinv, N);
  scan_bsums<<<1, 256, 0, stream>>>(bsum, boff, NB);
  write_csr<<<NB, 256, 0, stream>>>(deg_cnt, boff, csr_ptr, N, E);
  fill_gemm<<<eb + gemmb, 256, 0, stream>>>(src, dst, rank, csr_ptr, csr_src, E, eb,
                                            x, Wb, dinv, hb, N);
  aggregate<<<nAggBlocks, 256, 0, stream>>>(hb, csr_ptr, csr_src, dinv,
                                            conv_bias, (float4*)out, partials, N);
  finalize_stats<<<1, 1024, 0, stream>>>(partials, nAggBlocks, stats,
                                         (double)N * (double)F);
  int n4 = N * (F / 4);
  norm_prelu<<<(n4 + 255) / 256, 256, 0, stream>>>((float4*)out, stats, ln_w, ln_b, prelu_a, n4);
}